// Round 2
// baseline (907.649 us; speedup 1.0000x reference)
//
#include <hip/hip_runtime.h>
#include <math.h>

#define BDIM 512
#define T_STEPS 20

__device__ __forceinline__ float sigm(float v) { return 1.0f / (1.0f + expf(-v)); }
__device__ __forceinline__ float dot4(float4 a, float4 w, float acc) {
  acc = fmaf(a.x, w.x, acc);
  acc = fmaf(a.y, w.y, acc);
  acc = fmaf(a.z, w.z, acc);
  acc = fmaf(a.w, w.w, acc);
  return acc;
}

// One block per batch b (grid=128). 512 threads: node i = tid>>3 (64 nodes),
// sub-lane s = tid&7. A node's 8 lanes always live in ONE wave, so row-local
// LDS producer->consumer pairs need no barrier. 2 barriers per time step.
// waves_per_eu(2,2): 8 waves/block = 1 block/CU anyway; pins VGPR budget to
// 256 so the compiler cannot spill (round-1 spilled ~830 MB of scratch).
__global__ __attribute__((amdgpu_flat_work_group_size(BDIM, BDIM),
                          amdgpu_waves_per_eu(2, 2)))
void traj_disc(const float* __restrict__ x, const float* __restrict__ dmat,
               const float* __restrict__ bmat, const float* __restrict__ hmat,
               const float* __restrict__ maskp,
               const float* __restrict__ embW, const float* __restrict__ embb,
               const float* __restrict__ Wih, const float* __restrict__ Whh,
               const float* __restrict__ bih, const float* __restrict__ bhh,
               const float* __restrict__ dom,
               const float* __restrict__ e2aW, const float* __restrict__ e2ab,
               const float* __restrict__ spaW, const float* __restrict__ spab,
               const float* __restrict__ a2eW, const float* __restrict__ a2eb,
               const float* __restrict__ clsW, const float* __restrict__ clsb,
               const float* __restrict__ h0, const float* __restrict__ c0,
               float* __restrict__ out)
{
  // Pitches 52/36/68: odd multiples of 4 -> float4 rows stay 16B-aligned and
  // row-distinct accesses land in distinct bank groups.
  __shared__ __align__(16) float sg[128*52];   // [Wih(16) | Whh(32) | bias] per gate row
  __shared__ float sdom[144];
  __shared__ __align__(16) float se2a[32*36];
  __shared__ float se2ab[32];
  __shared__ __align__(16) float sspa[32*68];
  __shared__ float sspab[32];
  __shared__ __align__(16) float sa2e[32*36];
  __shared__ float sa2eb[32];
  __shared__ float sembW[32];
  __shared__ float sembb[16];
  __shared__ float sclsW[32];
  __shared__ float sclsb;
  __shared__ __align__(16) float sh[64*36];   // hidden state rows, pitch 36
  __shared__ __align__(16) float sa[64*36];   // attention-space a (reused for z)
  __shared__ float smk[64];

  const int tid = threadIdx.x;
  const int b = blockIdx.x;
  const int i = tid >> 3;                 // node 0..63
  const int s = tid & 7;                  // sub-lane 0..7
  const int rb = ((tid & 63) >> 3) << 3;  // row-base lane within wave

  // ---- one-time staging ----
  for (int idx = tid; idx < 2048; idx += BDIM) sg[(idx >> 4)*52 + (idx & 15)] = Wih[idx];
  for (int idx = tid; idx < 4096; idx += BDIM) sg[(idx >> 5)*52 + 16 + (idx & 31)] = Whh[idx];
  if (tid < 128) sg[tid*52 + 48] = bih[tid] + bhh[tid];
  if (tid < 144) sdom[tid] = dom[tid];
  for (int idx = tid; idx < 1024; idx += BDIM) se2a[(idx >> 5)*36 + (idx & 31)] = e2aW[idx];
  for (int idx = tid; idx < 2048; idx += BDIM) sspa[(idx >> 6)*68 + (idx & 63)] = spaW[idx];
  for (int idx = tid; idx < 1024; idx += BDIM) sa2e[(idx >> 5)*36 + (idx & 31)] = a2eW[idx];
  if (tid < 32) { se2ab[tid] = e2ab[tid]; sspab[tid] = spab[tid]; sa2eb[tid] = a2eb[tid];
                  sembW[tid] = embW[tid]; sclsW[tid] = clsW[tid]; }
  if (tid < 16) sembb[tid] = embb[tid];
  if (tid == 0) sclsb = clsb[0];
  for (int idx = tid; idx < 2048; idx += BDIM) sh[(idx >> 5)*36 + (idx & 31)] = h0[(size_t)b*2048 + idx];
  float cst[4];  // cell state: this thread owns c[i][s+8u]
  #pragma unroll
  for (int u = 0; u < 4; ++u) cst[u] = c0[(size_t)b*2048 + i*32 + s + 8*u];
  __syncthreads();

  const size_t nb = (size_t)b*64 + i;

  for (int t = 0; t < T_STEPS; ++t) {
    // ---- prefetch this step's globals (consumed in P1 / 3a) ----
    float x0 = x[(nb*20 + t)*2 + 0];
    float x1 = x[(nb*20 + t)*2 + 1];
    const size_t ebase = (nb*20 + t)*64;
    float dm8[8], bm8[8], hm8[8];
    #pragma unroll
    for (int jj = 0; jj < 8; ++jj) {
      dm8[jj] = dmat[ebase + s + 8*jj];
      bm8[jj] = bmat[ebase + s + 8*jj];
      hm8[jj] = hmat[ebase + s + 8*jj];
    }
    // smk write ordered vs cross-row readers by B3(t-1) before / B2(t) after
    if (tid < 64) smk[tid] = maskp[((size_t)b*64 + tid)*20 + t];

    // ---- P1: LSTM cell (gate order i,f,g,o); lane does hh = s+8u ----
    {
      float xv[16];
      #pragma unroll
      for (int e = 0; e < 16; ++e)
        xv[e] = fmaf(x0, sembW[2*e], fmaf(x1, sembW[2*e+1], sembb[e]));
      const float4* hrow = (const float4*)(sh + i*36);
      float4 hv[8];
      #pragma unroll
      for (int h4 = 0; h4 < 8; ++h4) hv[h4] = hrow[h4];
      float hl[4];
      #pragma unroll
      for (int u = 0; u < 4; ++u) {
        const int hh = s + 8*u;
        float acc[4];
        #pragma unroll
        for (int q = 0; q < 4; ++q) {
          const float* row = sg + (q*32 + hh)*52;
          float a0 = row[48];
          const float4* wi = (const float4*)row;
          #pragma unroll
          for (int e4 = 0; e4 < 4; ++e4) {
            float4 w = wi[e4];
            a0 = fmaf(xv[4*e4+0], w.x, a0);
            a0 = fmaf(xv[4*e4+1], w.y, a0);
            a0 = fmaf(xv[4*e4+2], w.z, a0);
            a0 = fmaf(xv[4*e4+3], w.w, a0);
          }
          const float4* wh = (const float4*)(row + 16);
          #pragma unroll
          for (int h4 = 0; h4 < 8; ++h4) a0 = dot4(hv[h4], wh[h4], a0);
          acc[q] = a0;
        }
        float ig = sigm(acc[0]);
        float fg = sigm(acc[1]);
        float gg = tanhf(acc[2]);
        float og = sigm(acc[3]);
        cst[u] = fmaf(fg, cst[u], ig*gg);
        hl[u] = og * tanhf(cst[u]);
      }
      // same-wave: all hv reads above precede these writes in program order
      #pragma unroll
      for (int u = 0; u < 4; ++u) sh[i*36 + s + 8*u] = hl[u];
    }

    // ---- P2: a = h @ enc2att_W^T + b (row-local) ----
    {
      const float4* hrow = (const float4*)(sh + i*36);
      #pragma unroll
      for (int u = 0; u < 4; ++u) {
        const int k = s + 8*u;
        float acc = se2ab[k];
        const float4* wr = (const float4*)(se2a + k*36);
        #pragma unroll
        for (int h4 = 0; h4 < 8; ++h4) acc = dot4(hrow[h4], wr[h4], acc);
        sa[i*36 + k] = acc;
      }
    }
    __syncthreads();  // B2: sa + smk visible to cross-row readers

    // ---- 3a: edge weights for this lane's 8 j's (registers only) ----
    float wv[8];
    float inv;
    {
      const float mi = smk[i];
      float rs = 0.0f;
      #pragma unroll
      for (int jj = 0; jj < 8; ++jj) {
        const int j = s + 8*jj;
        int ib = (int)floorf(bm8[jj] / 30.0f); ib = ib < 0 ? 0 : (ib > 11 ? 11 : ib);
        int ih = (int)floorf(hm8[jj] / 30.0f); ih = ih < 0 ? 0 : (ih > 11 ? 11 : ih);
        float wvx = fmaxf(sdom[ib*12 + ih] - dm8[jj], 0.0f) * (mi * smk[j]);
        wv[jj] = (j == i) ? 0.0f : wvx;
        rs += wv[jj];
      }
      rs += __shfl_xor(rs, 1);
      rs += __shfl_xor(rs, 2);
      rs += __shfl_xor(rs, 4);
      inv = 1.0f / (rs + 1e-12f);
    }

    // ---- 3b: att[i][m], lane owns m = 4s..4s+3 (one float4 acc), sum over
    // ALL j sequentially; w[i][j] pulled from row-mates via shfl. ----
    float4 att = make_float4(0.f, 0.f, 0.f, 0.f);
    {
      const float4* sa4 = (const float4*)sa;
      #pragma unroll
      for (int jj = 0; jj < 8; ++jj) {
        #pragma unroll
        for (int jl = 0; jl < 8; ++jl) {
          const float w = __shfl(wv[jj], rb + jl, 64);  // w[i][8*jj+jl]
          const float4 av = sa4[(8*jj + jl)*9 + s];     // a[j][4s..4s+3]
          att.x = fmaf(w, av.x, att.x);
          att.y = fmaf(w, av.y, att.y);
          att.z = fmaf(w, av.z, att.z);
          att.w = fmaf(w, av.w, att.w);
        }
      }
    }

    // ---- P4: z = tanh([a, att] @ spa_W^T + b), k = s+8u ----
    float zv[4];
    {
      const float4* arow = (const float4*)(sa + i*36);
      float acc[4];
      #pragma unroll
      for (int u = 0; u < 4; ++u) acc[u] = sspab[s + 8*u];
      #pragma unroll
      for (int m4 = 0; m4 < 8; ++m4) {
        const float4 av = arow[m4];
        #pragma unroll
        for (int u = 0; u < 4; ++u) {
          const float4 w = *(const float4*)(sspa + (s + 8*u)*68 + 4*m4);
          acc[u] = dot4(av, w, acc[u]);
        }
      }
      #pragma unroll
      for (int u = 0; u < 4; ++u) {
        const float4 w = *(const float4*)(sspa + (s + 8*u)*68 + 32 + 4*s);
        float p = att.x*w.x + att.y*w.y + att.z*w.z + att.w*w.w;
        p += __shfl_xor(p, 1);
        p += __shfl_xor(p, 2);
        p += __shfl_xor(p, 4);
        zv[u] = tanhf(acc[u] + p*inv);
      }
    }
    __syncthreads();  // B3: all cross-row sa reads done -> reuse sa for z
    #pragma unroll
    for (int u = 0; u < 4; ++u) sa[i*36 + s + 8*u] = zv[u];

    // ---- P5: h = z @ att2enc_W^T + b (row-local, no barrier) ----
    {
      const float4* zrow = (const float4*)(sa + i*36);
      #pragma unroll
      for (int u = 0; u < 4; ++u) {
        const int hh = s + 8*u;
        float acc = sa2eb[hh];
        const float4* wr = (const float4*)(sa2e + hh*36);
        #pragma unroll
        for (int m4 = 0; m4 < 8; ++m4) acc = dot4(zrow[m4], wr[m4], acc);
        sh[i*36 + hh] = acc;
      }
    }
  }
  __syncthreads();

  // ---- classifier head ----
  if (tid < 64) {
    float acc = sclsb;
    #pragma unroll
    for (int hh = 0; hh < 32; ++hh) acc = fmaf(sh[tid*36 + hh], sclsW[hh], acc);
    out[(size_t)b*64 + tid] = sigm(tanhf(acc));
  }
}

extern "C" void kernel_launch(void* const* d_in, const int* in_sizes, int n_in,
                              void* d_out, int out_size, void* d_ws, size_t ws_size,
                              hipStream_t stream) {
  (void)in_sizes; (void)n_in; (void)d_ws; (void)ws_size; (void)out_size;
  const float* x    = (const float*)d_in[0];
  const float* dmat = (const float*)d_in[1];
  const float* bmat = (const float*)d_in[2];
  const float* hmat = (const float*)d_in[3];
  const float* mask = (const float*)d_in[4];
  const float* embW = (const float*)d_in[5];
  const float* embb = (const float*)d_in[6];
  const float* Wih  = (const float*)d_in[7];
  const float* Whh  = (const float*)d_in[8];
  const float* bih  = (const float*)d_in[9];
  const float* bhh  = (const float*)d_in[10];
  const float* dom  = (const float*)d_in[11];
  const float* e2aW = (const float*)d_in[12];
  const float* e2ab = (const float*)d_in[13];
  const float* spaW = (const float*)d_in[14];
  const float* spab = (const float*)d_in[15];
  const float* a2eW = (const float*)d_in[16];
  const float* a2eb = (const float*)d_in[17];
  const float* clsW = (const float*)d_in[18];
  const float* clsb = (const float*)d_in[19];
  const float* h0   = (const float*)d_in[20];
  const float* c0   = (const float*)d_in[21];
  float* out = (float*)d_out;

  traj_disc<<<dim3(128), dim3(BDIM), 0, stream>>>(
      x, dmat, bmat, hmat, mask, embW, embb, Wih, Whh, bih, bhh, dom,
      e2aW, e2ab, spaW, spab, a2eW, a2eb, clsW, clsb, h0, c0, out);
}

// Round 3
// 375.834 us; speedup vs baseline: 2.4150x; 2.4150x over previous
//
#include <hip/hip_runtime.h>
#include <math.h>

#define BDIM 512
#define T_STEPS 20

__device__ __forceinline__ float sigm(float v) { return 1.0f / (1.0f + expf(-v)); }
__device__ __forceinline__ float dot4(float4 a, float4 w, float acc) {
  acc = fmaf(a.x, w.x, acc);
  acc = fmaf(a.y, w.y, acc);
  acc = fmaf(a.z, w.z, acc);
  acc = fmaf(a.w, w.w, acc);
  return acc;
}

// One block per batch b (grid=128). 512 threads: node i = tid>>3, sub-lane
// s = tid&7; a node's 8 lanes live in ONE wave. ZERO per-thread arrays:
// rounds 1-2 showed local arrays land in scratch (~1 float of HBM write+read
// per array element per step); everything is named scalars via macros, and
// shuffles appear only in straight-line code (convergent ops block unrolling).
__global__ __launch_bounds__(BDIM, 1)
void traj_disc(const float* __restrict__ x, const float* __restrict__ dmat,
               const float* __restrict__ bmat, const float* __restrict__ hmat,
               const float* __restrict__ maskp,
               const float* __restrict__ embW, const float* __restrict__ embb,
               const float* __restrict__ Wih, const float* __restrict__ Whh,
               const float* __restrict__ bih, const float* __restrict__ bhh,
               const float* __restrict__ dom,
               const float* __restrict__ e2aW, const float* __restrict__ e2ab,
               const float* __restrict__ spaW, const float* __restrict__ spab,
               const float* __restrict__ a2eW, const float* __restrict__ a2eb,
               const float* __restrict__ clsW, const float* __restrict__ clsb,
               const float* __restrict__ h0p, const float* __restrict__ c0p,
               float* __restrict__ out)
{
  // sg row r (pitch 36): [0..31]=Whh[r][:], [32]=M0, [33]=M1, [34]=bias'
  // where M = Wih @ embW (embedding folded into the LSTM x-projection) and
  // bias' = Wih @ embb + bih + bhh. Pitch 36: float4-aligned, rows map to
  // distinct bank groups (36r mod 32 = 4r).
  __shared__ __align__(16) float sg[128*36];
  __shared__ float sdom[144];
  __shared__ __align__(16) float se2a[32*36];
  __shared__ float se2ab[32];
  __shared__ __align__(16) float sspa[32*68];
  __shared__ float sspab[32];
  __shared__ __align__(16) float sa2e[32*36];
  __shared__ float sa2eb[32];
  __shared__ float sclsW[32];
  __shared__ float sclsb;
  __shared__ float sm[1280];                  // mask[b] as [n][t]
  __shared__ __align__(16) float sh[64*36];   // hidden rows, pitch 36
  __shared__ __align__(16) float sa[64*36];   // att-space a (reused for z)

  const int tid = threadIdx.x;
  const int b = blockIdx.x;
  const int i = tid >> 3;                 // node 0..63
  const int s = tid & 7;                  // sub-lane 0..7
  const int rb = ((tid & 63) >> 3) << 3;  // row-base lane within wave

  // ---- one-time staging ----
  for (int idx = tid; idx < 4096; idx += BDIM) sg[(idx >> 5)*36 + (idx & 31)] = Whh[idx];
  if (tid < 128) {
    float m0 = 0.f, m1 = 0.f, bb = bih[tid] + bhh[tid];
    #pragma unroll
    for (int e = 0; e < 16; ++e) {
      float wv_ = Wih[tid*16 + e];
      m0 = fmaf(wv_, embW[2*e],   m0);
      m1 = fmaf(wv_, embW[2*e+1], m1);
      bb = fmaf(wv_, embb[e],     bb);
    }
    sg[tid*36 + 32] = m0; sg[tid*36 + 33] = m1; sg[tid*36 + 34] = bb;
  }
  if (tid < 144) sdom[tid] = dom[tid];
  for (int idx = tid; idx < 1024; idx += BDIM) se2a[(idx >> 5)*36 + (idx & 31)] = e2aW[idx];
  for (int idx = tid; idx < 2048; idx += BDIM) sspa[(idx >> 6)*68 + (idx & 63)] = spaW[idx];
  for (int idx = tid; idx < 1024; idx += BDIM) sa2e[(idx >> 5)*36 + (idx & 31)] = a2eW[idx];
  if (tid < 32) { se2ab[tid] = e2ab[tid]; sspab[tid] = spab[tid]; sa2eb[tid] = a2eb[tid];
                  sclsW[tid] = clsW[tid]; }
  if (tid == 0) sclsb = clsb[0];
  for (int idx = tid; idx < 1280; idx += BDIM) sm[idx] = maskp[(size_t)b*1280 + idx];
  for (int idx = tid; idx < 2048; idx += BDIM) sh[(idx >> 5)*36 + (idx & 31)] = h0p[(size_t)b*2048 + idx];
  float c0r = c0p[(size_t)b*2048 + i*32 + s +  0];
  float c1r = c0p[(size_t)b*2048 + i*32 + s +  8];
  float c2r = c0p[(size_t)b*2048 + i*32 + s + 16];
  float c3r = c0p[(size_t)b*2048 + i*32 + s + 24];
  __syncthreads();

  const size_t nb = (size_t)b*64 + i;

  #pragma unroll 1
  for (int t = 0; t < T_STEPS; ++t) {
    const size_t ebase = (nb*20 + t)*64;
    const float x0v = x[(nb*20 + t)*2 + 0];
    const float x1v = x[(nb*20 + t)*2 + 1];
    // edge prefetch: 24 NAMED scalars (never an array)
#define EDGELD(jj) const float dm##jj = dmat[ebase + s + 8*(jj)]; \
                   const float bm##jj = bmat[ebase + s + 8*(jj)]; \
                   const float hm##jj = hmat[ebase + s + 8*(jj)];
    EDGELD(0) EDGELD(1) EDGELD(2) EDGELD(3) EDGELD(4) EDGELD(5) EDGELD(6) EDGELD(7)
#undef EDGELD

    // ---- P1: LSTM cell (gate rows i,f,g,o = q*32+hh), lane does hh=s+8u ----
    {
      const float4* hrow4 = (const float4*)(sh + i*36);
      const float4 h0_ = hrow4[0], h1_ = hrow4[1], h2_ = hrow4[2], h3_ = hrow4[3];
      const float4 h4_ = hrow4[4], h5_ = hrow4[5], h6_ = hrow4[6], h7_ = hrow4[7];
#define GDOT(q, hh, dst) { const float* r_ = sg + ((q)*32 + (hh))*36; \
      const float4 mb_ = *(const float4*)(r_ + 32); \
      float a_ = fmaf(x0v, mb_.x, fmaf(x1v, mb_.y, mb_.z)); \
      const float4* w_ = (const float4*)r_; \
      a_ = dot4(h0_, w_[0], a_); a_ = dot4(h1_, w_[1], a_); \
      a_ = dot4(h2_, w_[2], a_); a_ = dot4(h3_, w_[3], a_); \
      a_ = dot4(h4_, w_[4], a_); a_ = dot4(h5_, w_[5], a_); \
      a_ = dot4(h6_, w_[6], a_); a_ = dot4(h7_, w_[7], a_); \
      dst = a_; }
#define LSTM_U(u, creg) { const int hh_ = s + 8*(u); \
      float ai_, af_, ag_, ao_; \
      GDOT(0, hh_, ai_) GDOT(1, hh_, af_) GDOT(2, hh_, ag_) GDOT(3, hh_, ao_) \
      const float ig_ = sigm(ai_), fg_ = sigm(af_), gg_ = tanhf(ag_), og_ = sigm(ao_); \
      creg = fmaf(fg_, creg, ig_*gg_); \
      sh[i*36 + hh_] = og_ * tanhf(creg); }
      LSTM_U(0, c0r) LSTM_U(1, c1r) LSTM_U(2, c2r) LSTM_U(3, c3r)
#undef LSTM_U
#undef GDOT
    }

    // ---- P2: a = h @ enc2att_W^T + b (row-local; same-wave ordering) ----
    {
      const float4* hrow4 = (const float4*)(sh + i*36);
      const float4 g0_ = hrow4[0], g1_ = hrow4[1], g2_ = hrow4[2], g3_ = hrow4[3];
      const float4 g4_ = hrow4[4], g5_ = hrow4[5], g6_ = hrow4[6], g7_ = hrow4[7];
#define AOUT(u) { const int k_ = s + 8*(u); \
      float acc_ = se2ab[k_]; \
      const float4* wr_ = (const float4*)(se2a + k_*36); \
      acc_ = dot4(g0_, wr_[0], acc_); acc_ = dot4(g1_, wr_[1], acc_); \
      acc_ = dot4(g2_, wr_[2], acc_); acc_ = dot4(g3_, wr_[3], acc_); \
      acc_ = dot4(g4_, wr_[4], acc_); acc_ = dot4(g5_, wr_[5], acc_); \
      acc_ = dot4(g6_, wr_[6], acc_); acc_ = dot4(g7_, wr_[7], acc_); \
      sa[i*36 + k_] = acc_; }
      AOUT(0) AOUT(1) AOUT(2) AOUT(3)
#undef AOUT
    }
    __syncthreads();  // B2: sa visible to cross-row readers

    // ---- 3a: normalized edge weights wn0..wn7 (named scalars) ----
    const float mi_ = sm[i*20 + t];
    float rs = 0.0f;
#define WCOMP(jj) float wn##jj; { \
    int ib_ = (int)floorf(bm##jj * (1.0f/30.0f)); ib_ = ib_ < 0 ? 0 : (ib_ > 11 ? 11 : ib_); \
    int ih_ = (int)floorf(hm##jj * (1.0f/30.0f)); ih_ = ih_ < 0 ? 0 : (ih_ > 11 ? 11 : ih_); \
    float w_ = fmaxf(sdom[ib_*12 + ih_] - dm##jj, 0.0f) * (mi_ * sm[(s + 8*(jj))*20 + t]); \
    wn##jj = (s + 8*(jj) == i) ? 0.0f : w_; rs += wn##jj; }
    WCOMP(0) WCOMP(1) WCOMP(2) WCOMP(3) WCOMP(4) WCOMP(5) WCOMP(6) WCOMP(7)
#undef WCOMP
    rs += __shfl_xor(rs, 1); rs += __shfl_xor(rs, 2); rs += __shfl_xor(rs, 4);
    const float inv_ = 1.0f / (rs + 1e-12f);
    wn0 *= inv_; wn1 *= inv_; wn2 *= inv_; wn3 *= inv_;
    wn4 *= inv_; wn5 *= inv_; wn6 *= inv_; wn7 *= inv_;

    // ---- 3b: att[i][4s..4s+3] = sum_j wn[i][j] * a[j][4s..4s+3] ----
    float att_x = 0.f, att_y = 0.f, att_z = 0.f, att_w = 0.f;
#define ATTJ(jj, jl) { const float wq_ = __shfl(wn##jj, rb + (jl), 64); \
    const float4 av_ = *(const float4*)(sa + (8*(jj) + (jl))*36 + 4*s); \
    att_x = fmaf(wq_, av_.x, att_x); att_y = fmaf(wq_, av_.y, att_y); \
    att_z = fmaf(wq_, av_.z, att_z); att_w = fmaf(wq_, av_.w, att_w); }
#define ATTROW(jj) ATTJ(jj,0) ATTJ(jj,1) ATTJ(jj,2) ATTJ(jj,3) \
                   ATTJ(jj,4) ATTJ(jj,5) ATTJ(jj,6) ATTJ(jj,7)
    ATTROW(0) ATTROW(1) ATTROW(2) ATTROW(3)
    ATTROW(4) ATTROW(5) ATTROW(6) ATTROW(7)
#undef ATTROW
#undef ATTJ

    // gather the FULL att row (32 floats) per lane — fixes the R1/R2 bug of
    // reducing partials computed against different spa_W rows.
    float4 A0, A1, A2, A3, A4, A5, A6, A7;
#define GATH(c) { A##c.x = __shfl(att_x, rb + (c), 64); A##c.y = __shfl(att_y, rb + (c), 64); \
                  A##c.z = __shfl(att_z, rb + (c), 64); A##c.w = __shfl(att_w, rb + (c), 64); }
    GATH(0) GATH(1) GATH(2) GATH(3) GATH(4) GATH(5) GATH(6) GATH(7)
#undef GATH

    // ---- P4: z_k = tanh([a, att] . spa_W[k] + b), k = s+8u, fully local ----
    const float4* arow4 = (const float4*)(sa + i*36);
    const float4 a0_ = arow4[0], a1_ = arow4[1], a2_ = arow4[2], a3_ = arow4[3];
    const float4 a4_ = arow4[4], a5_ = arow4[5], a6_ = arow4[6], a7_ = arow4[7];
    float zv0, zv1, zv2, zv3;
#define ZCOMP(u, zdst) { const int k_ = s + 8*(u); \
    float acc_ = sspab[k_]; \
    const float4* wr_ = (const float4*)(sspa + k_*68); \
    acc_ = dot4(a0_, wr_[0], acc_); acc_ = dot4(a1_, wr_[1], acc_); \
    acc_ = dot4(a2_, wr_[2], acc_); acc_ = dot4(a3_, wr_[3], acc_); \
    acc_ = dot4(a4_, wr_[4], acc_); acc_ = dot4(a5_, wr_[5], acc_); \
    acc_ = dot4(a6_, wr_[6], acc_); acc_ = dot4(a7_, wr_[7], acc_); \
    acc_ = dot4(A0, wr_[8],  acc_); acc_ = dot4(A1, wr_[9],  acc_); \
    acc_ = dot4(A2, wr_[10], acc_); acc_ = dot4(A3, wr_[11], acc_); \
    acc_ = dot4(A4, wr_[12], acc_); acc_ = dot4(A5, wr_[13], acc_); \
    acc_ = dot4(A6, wr_[14], acc_); acc_ = dot4(A7, wr_[15], acc_); \
    zdst = tanhf(acc_); }
    ZCOMP(0, zv0) ZCOMP(1, zv1) ZCOMP(2, zv2) ZCOMP(3, zv3)
#undef ZCOMP
    __syncthreads();  // B3: all cross-row sa reads done -> reuse sa for z
    sa[i*36 + s +  0] = zv0;
    sa[i*36 + s +  8] = zv1;
    sa[i*36 + s + 16] = zv2;
    sa[i*36 + s + 24] = zv3;

    // ---- P5: h = z @ att2enc_W^T + b (row-local, same-wave) ----
    {
      const float4* zrow4 = (const float4*)(sa + i*36);
      const float4 z0_ = zrow4[0], z1_ = zrow4[1], z2_ = zrow4[2], z3_ = zrow4[3];
      const float4 z4_ = zrow4[4], z5_ = zrow4[5], z6_ = zrow4[6], z7_ = zrow4[7];
#define HOUT(u) { const int hh_ = s + 8*(u); \
      float acc_ = sa2eb[hh_]; \
      const float4* wr_ = (const float4*)(sa2e + hh_*36); \
      acc_ = dot4(z0_, wr_[0], acc_); acc_ = dot4(z1_, wr_[1], acc_); \
      acc_ = dot4(z2_, wr_[2], acc_); acc_ = dot4(z3_, wr_[3], acc_); \
      acc_ = dot4(z4_, wr_[4], acc_); acc_ = dot4(z5_, wr_[5], acc_); \
      acc_ = dot4(z6_, wr_[6], acc_); acc_ = dot4(z7_, wr_[7], acc_); \
      sh[i*36 + hh_] = acc_; }
      HOUT(0) HOUT(1) HOUT(2) HOUT(3)
#undef HOUT
    }
  }
  __syncthreads();

  // ---- classifier head ----
  if (tid < 64) {
    float acc = sclsb;
    #pragma unroll
    for (int hh = 0; hh < 32; ++hh) acc = fmaf(sh[tid*36 + hh], sclsW[hh], acc);
    out[(size_t)b*64 + tid] = sigm(tanhf(acc));
  }
}

extern "C" void kernel_launch(void* const* d_in, const int* in_sizes, int n_in,
                              void* d_out, int out_size, void* d_ws, size_t ws_size,
                              hipStream_t stream) {
  (void)in_sizes; (void)n_in; (void)d_ws; (void)ws_size; (void)out_size;
  const float* x    = (const float*)d_in[0];
  const float* dmat = (const float*)d_in[1];
  const float* bmat = (const float*)d_in[2];
  const float* hmat = (const float*)d_in[3];
  const float* mask = (const float*)d_in[4];
  const float* embW = (const float*)d_in[5];
  const float* embb = (const float*)d_in[6];
  const float* Wih  = (const float*)d_in[7];
  const float* Whh  = (const float*)d_in[8];
  const float* bih  = (const float*)d_in[9];
  const float* bhh  = (const float*)d_in[10];
  const float* dom  = (const float*)d_in[11];
  const float* e2aW = (const float*)d_in[12];
  const float* e2ab = (const float*)d_in[13];
  const float* spaW = (const float*)d_in[14];
  const float* spab = (const float*)d_in[15];
  const float* a2eW = (const float*)d_in[16];
  const float* a2eb = (const float*)d_in[17];
  const float* clsW = (const float*)d_in[18];
  const float* clsb = (const float*)d_in[19];
  const float* h0   = (const float*)d_in[20];
  const float* c0   = (const float*)d_in[21];
  float* out = (float*)d_out;

  traj_disc<<<dim3(128), dim3(BDIM), 0, stream>>>(
      x, dmat, bmat, hmat, mask, embW, embb, Wih, Whh, bih, bhh, dom,
      e2aW, e2ab, spaW, spab, a2eW, a2eb, clsW, clsb, h0, c0, out);
}

// Round 4
// 355.041 us; speedup vs baseline: 2.5565x; 1.0586x over previous
//
#include <hip/hip_runtime.h>
#include <math.h>

#define BDIM 1024
#define T_STEPS 20

// fast transcendentals: v_exp + v_rcp (~1e-7 abs err; threshold is 9.7e-3)
__device__ __forceinline__ float sigm(float v) {
  return __builtin_amdgcn_rcpf(1.0f + __expf(-v));
}
__device__ __forceinline__ float tanh_f(float v) {
  return 1.0f - 2.0f * __builtin_amdgcn_rcpf(1.0f + __expf(2.0f * v));
}
__device__ __forceinline__ float dot4(float4 a, float4 w, float acc) {
  acc = fmaf(a.x, w.x, acc);
  acc = fmaf(a.y, w.y, acc);
  acc = fmaf(a.z, w.z, acc);
  acc = fmaf(a.w, w.w, acc);
  return acc;
}

// One block per batch (grid=128). 1024 threads: node i = tid>>4, sub-lane
// s = tid&15; a node's 16 lanes live in ONE wave (4 nodes/wave). 4 waves/SIMD
// (vs 2 in the 512-thr version) to hide LDS/exp latency: barrier-locked waves
// stall at the same PCs, extra waves fill the gaps. ZERO per-thread arrays
// (R1/R2: local arrays = scratch = HBM). 2 barriers/step: every other
// producer->consumer pair is same-wave (wave-synchronous program order).
__global__ __launch_bounds__(BDIM)
void traj_disc(const float* __restrict__ x, const float* __restrict__ dmat,
               const float* __restrict__ bmat, const float* __restrict__ hmat,
               const float* __restrict__ maskp,
               const float* __restrict__ embW, const float* __restrict__ embb,
               const float* __restrict__ Wih, const float* __restrict__ Whh,
               const float* __restrict__ bih, const float* __restrict__ bhh,
               const float* __restrict__ dom,
               const float* __restrict__ e2aW, const float* __restrict__ e2ab,
               const float* __restrict__ spaW, const float* __restrict__ spab,
               const float* __restrict__ a2eW, const float* __restrict__ a2eb,
               const float* __restrict__ clsW, const float* __restrict__ clsb,
               const float* __restrict__ h0p, const float* __restrict__ c0p,
               float* __restrict__ out)
{
  // sg row r (pitch 36): [0..31]=Whh[r][:], [32]=M0,[33]=M1,[34]=bias'
  // (embedding folded: M = Wih@embW, bias' = Wih@embb + bih + bhh)
  __shared__ __align__(16) float sg[128*36];
  __shared__ float sdom[144];
  __shared__ __align__(16) float se2a[32*36];
  __shared__ float se2ab[32];
  __shared__ __align__(16) float sspa[32*68];
  __shared__ float sspab[32];
  __shared__ __align__(16) float sa2e[32*36];
  __shared__ float sa2eb[32];
  __shared__ float sclsW[32];
  __shared__ float sclsb;
  __shared__ float sm[1280];                  // mask[b] as [n][t]
  __shared__ __align__(16) float sh[64*36];   // h rows (carry + lstm temp)
  __shared__ __align__(16) float sa[64*72];   // [i][0..31]=a, [36..67]=att; reused for z
  __shared__ __align__(16) float sw[64*68];   // normalized edge weights w[i][j]

  const int tid = threadIdx.x;
  const int b = blockIdx.x;
  const int i = tid >> 4;   // node 0..63
  const int s = tid & 15;   // sub-lane 0..15

  // ---- one-time staging ----
  for (int idx = tid; idx < 4096; idx += BDIM) sg[(idx >> 5)*36 + (idx & 31)] = Whh[idx];
  if (tid < 128) {
    float m0 = 0.f, m1 = 0.f, bb = bih[tid] + bhh[tid];
    #pragma unroll
    for (int e = 0; e < 16; ++e) {
      float wv_ = Wih[tid*16 + e];
      m0 = fmaf(wv_, embW[2*e],   m0);
      m1 = fmaf(wv_, embW[2*e+1], m1);
      bb = fmaf(wv_, embb[e],     bb);
    }
    sg[tid*36 + 32] = m0; sg[tid*36 + 33] = m1; sg[tid*36 + 34] = bb;
  }
  if (tid < 144) sdom[tid] = dom[tid];
  for (int idx = tid; idx < 1024; idx += BDIM) se2a[(idx >> 5)*36 + (idx & 31)] = e2aW[idx];
  for (int idx = tid; idx < 2048; idx += BDIM) sspa[(idx >> 6)*68 + (idx & 63)] = spaW[idx];
  for (int idx = tid; idx < 1024; idx += BDIM) sa2e[(idx >> 5)*36 + (idx & 31)] = a2eW[idx];
  if (tid < 32) { se2ab[tid] = e2ab[tid]; sspab[tid] = spab[tid]; sa2eb[tid] = a2eb[tid];
                  sclsW[tid] = clsW[tid]; }
  if (tid == 0) sclsb = clsb[0];
  for (int idx = tid; idx < 1280; idx += BDIM) sm[idx] = maskp[(size_t)b*1280 + idx];
  for (int idx = tid; idx < 2048; idx += BDIM) sh[(idx >> 5)*36 + (idx & 31)] = h0p[(size_t)b*2048 + idx];
  float c0r = c0p[(size_t)b*2048 + i*32 + s];       // cell state, hh = s
  float c1r = c0p[(size_t)b*2048 + i*32 + s + 16];  // cell state, hh = s+16
  __syncthreads();

  const size_t nb = (size_t)b*64 + i;

  #pragma unroll 1
  for (int t = 0; t < T_STEPS; ++t) {
    const size_t ebase = (nb*20 + t)*64;
    const float x0v = x[(nb*20 + t)*2 + 0];
    const float x1v = x[(nb*20 + t)*2 + 1];
    // 12 NAMED edge scalars (never an array); lanes s consecutive -> coalesced
#define EDGELD(jj) const float dm##jj = dmat[ebase + s + 16*(jj)]; \
                   const float bm##jj = bmat[ebase + s + 16*(jj)]; \
                   const float hm##jj = hmat[ebase + s + 16*(jj)];
    EDGELD(0) EDGELD(1) EDGELD(2) EDGELD(3)
#undef EDGELD

    // ---- P1: LSTM cell; lane owns hh = s, s+16 (gate rows q*32+hh) ----
    {
      const float4* hrow4 = (const float4*)(sh + i*36);
      const float4 h0_ = hrow4[0], h1_ = hrow4[1], h2_ = hrow4[2], h3_ = hrow4[3];
      const float4 h4_ = hrow4[4], h5_ = hrow4[5], h6_ = hrow4[6], h7_ = hrow4[7];
#define GDOT(q, hh, dst) { const float* r_ = sg + ((q)*32 + (hh))*36; \
      const float4 mb_ = *(const float4*)(r_ + 32); \
      float a_ = fmaf(x0v, mb_.x, fmaf(x1v, mb_.y, mb_.z)); \
      const float4* w_ = (const float4*)r_; \
      a_ = dot4(h0_, w_[0], a_); a_ = dot4(h1_, w_[1], a_); \
      a_ = dot4(h2_, w_[2], a_); a_ = dot4(h3_, w_[3], a_); \
      a_ = dot4(h4_, w_[4], a_); a_ = dot4(h5_, w_[5], a_); \
      a_ = dot4(h6_, w_[6], a_); a_ = dot4(h7_, w_[7], a_); \
      dst = a_; }
#define LSTM_U(u, creg) { const int hh_ = s + 16*(u); \
      float ai_, af_, ag_, ao_; \
      GDOT(0, hh_, ai_) GDOT(1, hh_, af_) GDOT(2, hh_, ag_) GDOT(3, hh_, ao_) \
      const float ig_ = sigm(ai_), fg_ = sigm(af_), gg_ = tanh_f(ag_), og_ = sigm(ao_); \
      creg = fmaf(fg_, creg, ig_*gg_); \
      sh[i*36 + hh_] = og_ * tanh_f(creg); }
      LSTM_U(0, c0r) LSTM_U(1, c1r)
#undef LSTM_U
#undef GDOT
    }

    // ---- P2: a = h @ enc2att_W^T + b (row-local, same-wave) ----
    {
      const float4* hrow4 = (const float4*)(sh + i*36);
      const float4 g0_ = hrow4[0], g1_ = hrow4[1], g2_ = hrow4[2], g3_ = hrow4[3];
      const float4 g4_ = hrow4[4], g5_ = hrow4[5], g6_ = hrow4[6], g7_ = hrow4[7];
#define AOUT(u) { const int k_ = s + 16*(u); \
      float acc_ = se2ab[k_]; \
      const float4* wr_ = (const float4*)(se2a + k_*36); \
      acc_ = dot4(g0_, wr_[0], acc_); acc_ = dot4(g1_, wr_[1], acc_); \
      acc_ = dot4(g2_, wr_[2], acc_); acc_ = dot4(g3_, wr_[3], acc_); \
      acc_ = dot4(g4_, wr_[4], acc_); acc_ = dot4(g5_, wr_[5], acc_); \
      acc_ = dot4(g6_, wr_[6], acc_); acc_ = dot4(g7_, wr_[7], acc_); \
      sa[i*72 + k_] = acc_; }
      AOUT(0) AOUT(1)
#undef AOUT
    }
    __syncthreads();  // B2: sa (a) visible to cross-wave readers (3b)

    // ---- 3a: normalized edge weights -> sw[i][j] (row-local, same-wave) ----
    {
      const float mi_ = sm[i*20 + t];
      float rs = 0.0f;
#define WCOMP(jj) float wn##jj; { \
      int ib_ = (int)floorf(bm##jj * (1.0f/30.0f)); ib_ = ib_ < 0 ? 0 : (ib_ > 11 ? 11 : ib_); \
      int ih_ = (int)floorf(hm##jj * (1.0f/30.0f)); ih_ = ih_ < 0 ? 0 : (ih_ > 11 ? 11 : ih_); \
      float w_ = fmaxf(sdom[ib_*12 + ih_] - dm##jj, 0.0f) * (mi_ * sm[(s + 16*(jj))*20 + t]); \
      wn##jj = (s + 16*(jj) == i) ? 0.0f : w_; rs += wn##jj; }
      WCOMP(0) WCOMP(1) WCOMP(2) WCOMP(3)
#undef WCOMP
      rs += __shfl_xor(rs, 1); rs += __shfl_xor(rs, 2);
      rs += __shfl_xor(rs, 4); rs += __shfl_xor(rs, 8);
      const float inv_ = __builtin_amdgcn_rcpf(rs + 1e-12f);
      sw[i*68 + s +  0] = wn0 * inv_;
      sw[i*68 + s + 16] = wn1 * inv_;
      sw[i*68 + s + 32] = wn2 * inv_;
      sw[i*68 + s + 48] = wn3 * inv_;
    }

    // ---- 3b: att[i][m] — lane (p = s>>3) sums its j-half for m4 = s&7;
    // combine halves with 4 shfl_xor(8). w from LDS (no bpermute storm). ----
    {
      const int p  = s >> 3;
      const int m8 = s & 7;
      const float* wrow = sw + i*68 + 32*p;
      const float4 w0_ = *(const float4*)(wrow +  0);
      const float4 w1_ = *(const float4*)(wrow +  4);
      const float4 w2_ = *(const float4*)(wrow +  8);
      const float4 w3_ = *(const float4*)(wrow + 12);
      const float4 w4_ = *(const float4*)(wrow + 16);
      const float4 w5_ = *(const float4*)(wrow + 20);
      const float4 w6_ = *(const float4*)(wrow + 24);
      const float4 w7_ = *(const float4*)(wrow + 28);
      float ax = 0.f, ay = 0.f, az = 0.f, aw = 0.f;
      const float* abase = sa + 4*m8 + (size_t)(32*p)*72;
#define AJ(c, r, wv) { const float4 av_ = *(const float4*)(abase + (4*(c) + (r))*72); \
      ax = fmaf(wv, av_.x, ax); ay = fmaf(wv, av_.y, ay); \
      az = fmaf(wv, av_.z, az); aw = fmaf(wv, av_.w, aw); }
#define AJ4(c, wreg) AJ(c, 0, wreg.x) AJ(c, 1, wreg.y) AJ(c, 2, wreg.z) AJ(c, 3, wreg.w)
      AJ4(0, w0_) AJ4(1, w1_) AJ4(2, w2_) AJ4(3, w3_)
      AJ4(4, w4_) AJ4(5, w5_) AJ4(6, w6_) AJ4(7, w7_)
#undef AJ4
#undef AJ
      ax += __shfl_xor(ax, 8); ay += __shfl_xor(ay, 8);
      az += __shfl_xor(az, 8); aw += __shfl_xor(aw, 8);
      if (p == 0) {
        float* d = sa + i*72 + 36 + 4*m8;
        d[0] = ax; d[1] = ay; d[2] = az; d[3] = aw;
      }
    }
    // att written by own row's lanes (same wave) -> P4 needs no barrier

    // ---- P4: z_k = tanh([a|att][i] . spa_W[k] + b), k = s+16u ----
    float zv0, zv1;
    {
      const float4* arow4 = (const float4*)(sa + i*72);
      const float4 a0_ = arow4[0], a1_ = arow4[1], a2_ = arow4[2], a3_ = arow4[3];
      const float4 a4_ = arow4[4], a5_ = arow4[5], a6_ = arow4[6], a7_ = arow4[7];
      const float4* trow4 = (const float4*)(sa + i*72 + 36);
      const float4 t0_ = trow4[0], t1_ = trow4[1], t2_ = trow4[2], t3_ = trow4[3];
      const float4 t4_ = trow4[4], t5_ = trow4[5], t6_ = trow4[6], t7_ = trow4[7];
#define ZCOMP(u, zdst) { const int k_ = s + 16*(u); \
      float acc_ = sspab[k_]; \
      const float4* wr_ = (const float4*)(sspa + k_*68); \
      acc_ = dot4(a0_, wr_[0], acc_); acc_ = dot4(a1_, wr_[1], acc_); \
      acc_ = dot4(a2_, wr_[2], acc_); acc_ = dot4(a3_, wr_[3], acc_); \
      acc_ = dot4(a4_, wr_[4], acc_); acc_ = dot4(a5_, wr_[5], acc_); \
      acc_ = dot4(a6_, wr_[6], acc_); acc_ = dot4(a7_, wr_[7], acc_); \
      acc_ = dot4(t0_, wr_[8],  acc_); acc_ = dot4(t1_, wr_[9],  acc_); \
      acc_ = dot4(t2_, wr_[10], acc_); acc_ = dot4(t3_, wr_[11], acc_); \
      acc_ = dot4(t4_, wr_[12], acc_); acc_ = dot4(t5_, wr_[13], acc_); \
      acc_ = dot4(t6_, wr_[14], acc_); acc_ = dot4(t7_, wr_[15], acc_); \
      zdst = tanh_f(acc_); }
      ZCOMP(0, zv0) ZCOMP(1, zv1)
#undef ZCOMP
    }
    __syncthreads();  // B4: all cross-wave reads of sa(a) done -> reuse for z
    sa[i*72 + s]      = zv0;
    sa[i*72 + s + 16] = zv1;

    // ---- P5: h = z @ att2enc_W^T + b (row-local, same-wave) ----
    {
      const float4* zrow4 = (const float4*)(sa + i*72);
      const float4 z0_ = zrow4[0], z1_ = zrow4[1], z2_ = zrow4[2], z3_ = zrow4[3];
      const float4 z4_ = zrow4[4], z5_ = zrow4[5], z6_ = zrow4[6], z7_ = zrow4[7];
#define HOUT(u) { const int k_ = s + 16*(u); \
      float acc_ = sa2eb[k_]; \
      const float4* wr_ = (const float4*)(sa2e + k_*36); \
      acc_ = dot4(z0_, wr_[0], acc_); acc_ = dot4(z1_, wr_[1], acc_); \
      acc_ = dot4(z2_, wr_[2], acc_); acc_ = dot4(z3_, wr_[3], acc_); \
      acc_ = dot4(z4_, wr_[4], acc_); acc_ = dot4(z5_, wr_[5], acc_); \
      acc_ = dot4(z6_, wr_[6], acc_); acc_ = dot4(z7_, wr_[7], acc_); \
      sh[i*36 + k_] = acc_; }
      HOUT(0) HOUT(1)
#undef HOUT
    }
    // next step: P1 reads sh row i (same wave), P2 same; no loop-top barrier
  }
  __syncthreads();

  // ---- classifier head ----
  if (tid < 64) {
    float acc = sclsb;
    #pragma unroll
    for (int hh = 0; hh < 32; ++hh) acc = fmaf(sh[tid*36 + hh], sclsW[hh], acc);
    out[(size_t)b*64 + tid] = sigm(tanh_f(acc));
  }
}

extern "C" void kernel_launch(void* const* d_in, const int* in_sizes, int n_in,
                              void* d_out, int out_size, void* d_ws, size_t ws_size,
                              hipStream_t stream) {
  (void)in_sizes; (void)n_in; (void)d_ws; (void)ws_size; (void)out_size;
  const float* x    = (const float*)d_in[0];
  const float* dmat = (const float*)d_in[1];
  const float* bmat = (const float*)d_in[2];
  const float* hmat = (const float*)d_in[3];
  const float* mask = (const float*)d_in[4];
  const float* embW = (const float*)d_in[5];
  const float* embb = (const float*)d_in[6];
  const float* Wih  = (const float*)d_in[7];
  const float* Whh  = (const float*)d_in[8];
  const float* bih  = (const float*)d_in[9];
  const float* bhh  = (const float*)d_in[10];
  const float* dom  = (const float*)d_in[11];
  const float* e2aW = (const float*)d_in[12];
  const float* e2ab = (const float*)d_in[13];
  const float* spaW = (const float*)d_in[14];
  const float* spab = (const float*)d_in[15];
  const float* a2eW = (const float*)d_in[16];
  const float* a2eb = (const float*)d_in[17];
  const float* clsW = (const float*)d_in[18];
  const float* clsb = (const float*)d_in[19];
  const float* h0   = (const float*)d_in[20];
  const float* c0   = (const float*)d_in[21];
  float* out = (float*)d_out;

  traj_disc<<<dim3(128), dim3(BDIM), 0, stream>>>(
      x, dmat, bmat, hmat, mask, embW, embb, Wih, Whh, bih, bhh, dom,
      e2aW, e2ab, spaW, spab, a2eW, a2eb, clsW, clsb, h0, c0, out);
}